// Round 2
// baseline (261.481 us; speedup 1.0000x reference)
//
#include <hip/hip_runtime.h>
#include <math.h>

#define LOOKBACK 336
#define NFEAT    164
#define HORIZON  96
#define DMODEL   64
#define DSTATE   16
#define DINNER   128
#define DTRANK   4
#define MLPH     64
#define BATCH    512
#define TC       16      // timesteps per chunk; 21*16 = 336
#define NCHUNK   21
#define XCP      132     // padded row stride (breaks 128-stride bank aliasing)

__device__ __forceinline__ float fast_rcp(float x) { return __builtin_amdgcn_rcpf(x); }
__device__ __forceinline__ float silu_f(float x) {
    return x * fast_rcp(1.f + __expf(-x));
}
__device__ __forceinline__ float softplus_f(float x) {
    return (x > 15.f) ? x : __logf(1.f + __expf(x));
}

// depthwise causal conv4 + silu for one chunk into xcbuf[TC][XCP]
__device__ __forceinline__ void conv_phase(
    int tbase, float* __restrict__ xcbuf, const float* __restrict__ xr,
    int par, int dA1, float w1d, float w0d,
    float cw0, float cw1, float cw2, float cw3, float cb,
    float* __restrict__ xc_last)
{
    if (tbase >= 3) {   // fast path: all taps in range
        #pragma unroll
        for (int ii = 0; ii < TC/2; ++ii) {
            int tt = par + 2*ii;
            int t  = tbase + tt;
            float e0 = fmaf(xr[t-3], w1d, w0d);
            float e1 = fmaf(xr[t-2], w1d, w0d);
            float e2 = fmaf(xr[t-1], w1d, w0d);
            float e3 = fmaf(xr[t  ], w1d, w0d);
            float acc = cb + e0*cw0 + e1*cw1 + e2*cw2 + e3*cw3;
            float v = silu_f(acc);
            xcbuf[tt*XCP + dA1] = v;
            if (t == LOOKBACK-1) xc_last[dA1] = v;
        }
    } else {            // chunk 0: guard negative taps
        #pragma unroll
        for (int ii = 0; ii < TC/2; ++ii) {
            int tt = par + 2*ii;
            int t  = tbase + tt;
            float acc = cb;
            if (t-3 >= 0) acc = fmaf(fmaf(xr[t-3], w1d, w0d), cw0, acc);
            if (t-2 >= 0) acc = fmaf(fmaf(xr[t-2], w1d, w0d), cw1, acc);
            if (t-1 >= 0) acc = fmaf(fmaf(xr[t-1], w1d, w0d), cw2, acc);
            acc = fmaf(fmaf(xr[t], w1d, w0d), cw3, acc);
            xcbuf[tt*XCP + dA1] = silu_f(acc);
        }
    }
}

__global__ __launch_bounds__(256, 4) void mamba_fused(
    const float* __restrict__ x_raw,      // (512,336)
    const float* __restrict__ x_features, // (512,164)
    const float* __restrict__ embed_W,    // (1,64)
    const float* __restrict__ embed_b,    // (64)
    const float* __restrict__ in_W,       // (64,256)
    const float* __restrict__ conv_W,     // (128,4)
    const float* __restrict__ conv_b,     // (128)
    const float* __restrict__ xproj_W,    // (128,36)
    const float* __restrict__ dt_W,       // (4,128)
    const float* __restrict__ dt_b,       // (128)
    const float* __restrict__ A_log,      // (128,16)
    const float* __restrict__ Dvec,       // (128)
    const float* __restrict__ out_W,      // (128,64)
    const float* __restrict__ mlp_W1,     // (164,64)
    const float* __restrict__ mlp_b1,     // (64)
    const float* __restrict__ mlp_W2,     // (64,32)
    const float* __restrict__ mlp_b2,     // (32)
    const float* __restrict__ head_W,     // (96,96)
    const float* __restrict__ head_b,     // (96)
    float* __restrict__ out)              // (512,96)
{
    __shared__ __align__(16) float xr[LOOKBACK];
    __shared__ __align__(16) float w1s[2*DINNER];
    __shared__ __align__(16) float w0s[2*DINNER];
    __shared__ __align__(16) float xprojT[20][XCP];   // transposed cols 0..19, padded
    __shared__ __align__(16) float xc_s[2][TC][XCP];  // double-buffered conv output
    __shared__ __align__(16) float Bs[TC][DSTATE];
    __shared__ __align__(16) float dtraw[TC][DTRANK];
    __shared__ __align__(16) float xc_last[DINNER];
    __shared__ __align__(16) float zsil[DINNER];
    __shared__ __align__(16) float Cl[DSTATE];
    __shared__ __align__(16) float yv[DINNER];
    __shared__ __align__(16) float hfin[96];          // [0..63] mamba, [64..95] mlp
    __shared__ __align__(16) float mlph[MLPH];

    const int tid = threadIdx.x;
    const int b   = blockIdx.x;

    // ---------------- prologue ----------------
    for (int i = tid; i < LOOKBACK; i += 256) xr[i] = x_raw[b*LOOKBACK + i];

    {   // rank-1 embed folded through in_W; column j = tid
        float a1 = 0.f, a0 = 0.f;
        for (int dm = 0; dm < DMODEL; ++dm) {
            float w = in_W[dm*(2*DINNER) + tid];
            a1 += embed_W[dm] * w;
            a0 += embed_b[dm] * w;
        }
        w1s[tid] = a1; w0s[tid] = a0;
    }
    for (int idx = tid; idx < 20*DINNER; idx += 256) {
        int jj = idx >> 7, d = idx & 127;
        xprojT[jj][d] = xproj_W[d*36 + jj];
    }

    // MLP stage 1
    if (tid < MLPH) {
        float acc = mlp_b1[tid];
        const float* xf = x_features + b*NFEAT;
        for (int f = 0; f < NFEAT; ++f) acc += xf[f]*mlp_W1[f*MLPH + tid];
        mlph[tid] = fmaxf(acc, 0.f);
    }
    __syncthreads();

    // per-thread constants (after barrier: w1s/w0s valid)
    const int   dA1 = tid & 127;
    const int   par = tid >> 7;
    const float w1d = w1s[dA1], w0d = w0s[dA1];
    const float cw0 = conv_W[dA1*4+0], cw1 = conv_W[dA1*4+1],
                cw2 = conv_W[dA1*4+2], cw3 = conv_W[dA1*4+3];
    const float cb  = conv_b[dA1];

    // scan-thread constants: d = tid>>1, states n0..n0+7
    const int dB = tid >> 1;
    const int n0 = (tid & 1) * 8;
    const float dtw0 = dt_W[0*DINNER + dB], dtw1 = dt_W[1*DINNER + dB],
                dtw2 = dt_W[2*DINNER + dB], dtw3 = dt_W[3*DINNER + dB];
    const float dtb_r = dt_b[dB];
    float Areg[8], h[8];
    {
        float4 al0 = *(const float4*)&A_log[dB*DSTATE + n0];
        float4 al1 = *(const float4*)&A_log[dB*DSTATE + n0 + 4];
        Areg[0] = -__expf(al0.x); Areg[1] = -__expf(al0.y);
        Areg[2] = -__expf(al0.z); Areg[3] = -__expf(al0.w);
        Areg[4] = -__expf(al1.x); Areg[5] = -__expf(al1.y);
        Areg[6] = -__expf(al1.z); Areg[7] = -__expf(al1.w);
    }
    #pragma unroll
    for (int i = 0; i < 8; ++i) h[i] = 0.f;

    // MLP stage 2 (mlph barrier-covered)
    if (tid < 32) {
        float acc = mlp_b2[tid];
        for (int k = 0; k < MLPH; ++k) acc += mlph[k]*mlp_W2[k*32 + tid];
        hfin[64 + tid] = acc;
    }

    // conv for chunk 0 into buffer 0
    conv_phase(0, &xc_s[0][0][0], xr, par, dA1, w1d, w0d, cw0, cw1, cw2, cw3, cb, xc_last);
    __syncthreads();

    // ---------------- main loop: 2 barriers per chunk ----------------
    for (int c = 0; c < NCHUNK; ++c) {
        const int buf = c & 1;
        const float* __restrict__ xcb = &xc_s[buf][0][0];

        // A2: [TC x 128] @ [128 x 20] -> dtraw(4) + Bs(16). 1x2 tiles, 160 threads.
        if (tid < 160) {
            const int tt = tid / 10;
            const int j0 = (tid - tt*10) * 2;
            float a0 = 0.f, a1 = 0.f;
            const float* xrow = xcb + tt*XCP;
            const float* p0   = &xprojT[j0][0];
            const float* p1   = &xprojT[j0+1][0];
            #pragma unroll 4
            for (int d = 0; d < DINNER; d += 4) {
                float4 xv = *(const float4*)(xrow + d);
                float4 q0 = *(const float4*)(p0 + d);
                float4 q1 = *(const float4*)(p1 + d);
                a0 += xv.x*q0.x + xv.y*q0.y + xv.z*q0.z + xv.w*q0.w;
                a1 += xv.x*q1.x + xv.y*q1.y + xv.z*q1.z + xv.w*q1.w;
            }
            if (j0 < 4) { float2 r = {a0, a1}; *(float2*)&dtraw[tt][j0]   = r; }
            else        { float2 r = {a0, a1}; *(float2*)&Bs[tt][j0-4]    = r; }
        }
        __syncthreads();

        // B: sequential scan with inline delta (softplus) — 8 states/thread
        #pragma unroll 2
        for (int tt = 0; tt < TC; ++tt) {
            float4 dr = *(const float4*)&dtraw[tt][0];   // broadcast
            float dv = dtb_r + dr.x*dtw0 + dr.y*dtw1 + dr.z*dtw2 + dr.w*dtw3;
            float dl = softplus_f(dv);
            float ux = dl * xcb[tt*XCP + dB];
            float4 b0 = *(const float4*)&Bs[tt][n0];
            float4 b1 = *(const float4*)&Bs[tt][n0 + 4];
            h[0] = __expf(dl*Areg[0])*h[0] + ux*b0.x;
            h[1] = __expf(dl*Areg[1])*h[1] + ux*b0.y;
            h[2] = __expf(dl*Areg[2])*h[2] + ux*b0.z;
            h[3] = __expf(dl*Areg[3])*h[3] + ux*b0.w;
            h[4] = __expf(dl*Areg[4])*h[4] + ux*b1.x;
            h[5] = __expf(dl*Areg[5])*h[5] + ux*b1.y;
            h[6] = __expf(dl*Areg[6])*h[6] + ux*b1.z;
            h[7] = __expf(dl*Areg[7])*h[7] + ux*b1.w;
        }

        // conv for next chunk into the other buffer (same basic block as scan:
        // independent work the scheduler can interleave into exp latency)
        if (c + 1 < NCHUNK) {
            conv_phase((c+1)*TC, &xc_s[1-buf][0][0], xr, par, dA1,
                       w1d, w0d, cw0, cw1, cw2, cw3, cb, xc_last);
        }
        __syncthreads();   // covers: scan's dtraw/Bs reads vs next A2 writes;
                           // next-buffer conv writes vs next A2 reads
    }

    // ---------------- epilogue (t = 335 only) ----------------
    if (tid < DINNER) {   // z-gate
        float zv = fmaf(xr[LOOKBACK-1], w1s[DINNER+tid], w0s[DINNER+tid]);
        zsil[tid] = silu_f(zv);
    }
    if (tid < DSTATE) {   // C at t=335
        float acc = 0.f;
        for (int d = 0; d < DINNER; ++d) acc += xc_last[d]*xproj_W[d*36 + 20 + tid];
        Cl[tid] = acc;
    }
    __syncthreads();

    {   // y[d] = h·C + xc_last*D, gated by silu(z)
        float part = 0.f;
        #pragma unroll
        for (int i = 0; i < 8; ++i) part += h[i]*Cl[n0 + i];
        float other = __shfl_xor(part, 1);
        if ((tid & 1) == 0) {
            float y = part + other + xc_last[dB]*Dvec[dB];
            yv[dB] = y * zsil[dB];
        }
    }
    __syncthreads();

    if (tid < DMODEL) {   // out projection
        float acc = 0.f;
        for (int d = 0; d < DINNER; ++d) acc += yv[d]*out_W[d*DMODEL + tid];
        hfin[tid] = acc;
    }
    __syncthreads();

    if (tid < HORIZON) {  // head
        float acc = head_b[tid];
        for (int i = 0; i < 96; ++i) acc += hfin[i]*head_W[i*HORIZON + tid];
        out[b*HORIZON + tid] = acc;
    }
}

extern "C" void kernel_launch(void* const* d_in, const int* in_sizes, int n_in,
                              void* d_out, int out_size, void* d_ws, size_t ws_size,
                              hipStream_t stream) {
    (void)in_sizes; (void)n_in; (void)d_ws; (void)ws_size; (void)out_size;
    mamba_fused<<<BATCH, 256, 0, stream>>>(
        (const float*)d_in[0],  (const float*)d_in[1],  (const float*)d_in[2],
        (const float*)d_in[3],  (const float*)d_in[4],  (const float*)d_in[5],
        (const float*)d_in[6],  (const float*)d_in[7],  (const float*)d_in[8],
        (const float*)d_in[9],  (const float*)d_in[10], (const float*)d_in[11],
        (const float*)d_in[12], (const float*)d_in[13], (const float*)d_in[14],
        (const float*)d_in[15], (const float*)d_in[16], (const float*)d_in[17],
        (const float*)d_in[18], (float*)d_out);
}

// Round 3
// 212.494 us; speedup vs baseline: 1.2305x; 1.2305x over previous
//
#include <hip/hip_runtime.h>
#include <math.h>

#define LOOKBACK 336
#define NFEAT    164
#define HORIZON  96
#define DMODEL   64
#define DSTATE   16
#define DINNER   128
#define DTRANK   4
#define MLPH     64
#define BATCH    512
#define TC       48      // timesteps per chunk; 7*48 = 336
#define NCHUNK   7
#define XCP      132     // padded row stride (breaks 128-stride bank aliasing)

__device__ __forceinline__ float fast_rcp(float x) { return __builtin_amdgcn_rcpf(x); }
__device__ __forceinline__ float silu_f(float x) {
    return x * fast_rcp(1.f + __expf(-x));
}
__device__ __forceinline__ float softplus_f(float x) {
    return (x > 15.f) ? x : __logf(1.f + __expf(x));
}

// depthwise causal conv4 + silu for one chunk into xcbuf[TC][XCP]
__device__ __forceinline__ void conv_phase(
    int tbase, float* __restrict__ xcbuf, const float* __restrict__ xr,
    int par, int dA1, float w1d, float w0d,
    float cw0, float cw1, float cw2, float cw3, float cb,
    float* __restrict__ xc_last)
{
    if (tbase >= 3) {   // fast path: all taps in range
        #pragma unroll 4
        for (int ii = 0; ii < TC/2; ++ii) {
            int tt = par + 2*ii;
            int t  = tbase + tt;
            float e0 = fmaf(xr[t-3], w1d, w0d);
            float e1 = fmaf(xr[t-2], w1d, w0d);
            float e2 = fmaf(xr[t-1], w1d, w0d);
            float e3 = fmaf(xr[t  ], w1d, w0d);
            float acc = cb + e0*cw0 + e1*cw1 + e2*cw2 + e3*cw3;
            float v = silu_f(acc);
            xcbuf[tt*XCP + dA1] = v;
            if (t == LOOKBACK-1) xc_last[dA1] = v;
        }
    } else {            // chunk 0: guard negative taps
        #pragma unroll 4
        for (int ii = 0; ii < TC/2; ++ii) {
            int tt = par + 2*ii;
            int t  = tbase + tt;
            float acc = cb;
            if (t-3 >= 0) acc = fmaf(fmaf(xr[t-3], w1d, w0d), cw0, acc);
            if (t-2 >= 0) acc = fmaf(fmaf(xr[t-2], w1d, w0d), cw1, acc);
            if (t-1 >= 0) acc = fmaf(fmaf(xr[t-1], w1d, w0d), cw2, acc);
            acc = fmaf(fmaf(xr[t], w1d, w0d), cw3, acc);
            xcbuf[tt*XCP + dA1] = silu_f(acc);
        }
    }
}

__global__ __launch_bounds__(256, 2) void mamba_fused(
    const float* __restrict__ x_raw,      // (512,336)
    const float* __restrict__ x_features, // (512,164)
    const float* __restrict__ embed_W,    // (1,64)
    const float* __restrict__ embed_b,    // (64)
    const float* __restrict__ in_W,       // (64,256)
    const float* __restrict__ conv_W,     // (128,4)
    const float* __restrict__ conv_b,     // (128)
    const float* __restrict__ xproj_W,    // (128,36)
    const float* __restrict__ dt_W,       // (4,128)
    const float* __restrict__ dt_b,       // (128)
    const float* __restrict__ A_log,      // (128,16)
    const float* __restrict__ Dvec,       // (128)
    const float* __restrict__ out_W,      // (128,64)
    const float* __restrict__ mlp_W1,     // (164,64)
    const float* __restrict__ mlp_b1,     // (64)
    const float* __restrict__ mlp_W2,     // (64,32)
    const float* __restrict__ mlp_b2,     // (32)
    const float* __restrict__ head_W,     // (96,96)
    const float* __restrict__ head_b,     // (96)
    float* __restrict__ out)              // (512,96)
{
    __shared__ __align__(16) float xr[LOOKBACK];
    __shared__ __align__(16) float w1s[2*DINNER];
    __shared__ __align__(16) float w0s[2*DINNER];
    __shared__ __align__(16) float xprojT[20][XCP];   // transposed cols 0..19, padded
    __shared__ __align__(16) float xc_s[2][TC][XCP];  // double-buffered conv output
    __shared__ __align__(16) float Bs[TC][DSTATE];
    __shared__ __align__(16) float dtraw[TC][DTRANK];
    __shared__ __align__(16) float xc_last[DINNER];
    __shared__ __align__(16) float zsil[DINNER];
    __shared__ __align__(16) float Cl[DSTATE];
    __shared__ __align__(16) float yv[DINNER];
    __shared__ __align__(16) float hfin[96];          // [0..63] mamba, [64..95] mlp
    __shared__ __align__(16) float mlph[MLPH];

    const int tid = threadIdx.x;
    const int b   = blockIdx.x;

    // ---------------- prologue ----------------
    for (int i = tid; i < LOOKBACK; i += 256) xr[i] = x_raw[b*LOOKBACK + i];

    {   // rank-1 embed folded through in_W; column j = tid
        float a1 = 0.f, a0 = 0.f;
        for (int dm = 0; dm < DMODEL; ++dm) {
            float w = in_W[dm*(2*DINNER) + tid];
            a1 += embed_W[dm] * w;
            a0 += embed_b[dm] * w;
        }
        w1s[tid] = a1; w0s[tid] = a0;
    }
    for (int idx = tid; idx < 20*DINNER; idx += 256) {
        int jj = idx >> 7, d = idx & 127;
        xprojT[jj][d] = xproj_W[d*36 + jj];
    }

    // MLP stage 1
    if (tid < MLPH) {
        float acc = mlp_b1[tid];
        const float* xf = x_features + b*NFEAT;
        for (int f = 0; f < NFEAT; ++f) acc += xf[f]*mlp_W1[f*MLPH + tid];
        mlph[tid] = fmaxf(acc, 0.f);
    }
    __syncthreads();

    // per-thread constants (after barrier: w1s/w0s valid)
    const int   dA1 = tid & 127;
    const int   par = tid >> 7;
    const float w1d = w1s[dA1], w0d = w0s[dA1];
    const float cw0 = conv_W[dA1*4+0], cw1 = conv_W[dA1*4+1],
                cw2 = conv_W[dA1*4+2], cw3 = conv_W[dA1*4+3];
    const float cb  = conv_b[dA1];

    // scan-thread constants: d = tid>>1, states n0..n0+7
    const int dB = tid >> 1;
    const int n0 = (tid & 1) * 8;
    const float dtw0 = dt_W[0*DINNER + dB], dtw1 = dt_W[1*DINNER + dB],
                dtw2 = dt_W[2*DINNER + dB], dtw3 = dt_W[3*DINNER + dB];
    const float dtb_r = dt_b[dB];
    float Areg[8], h[8];
    bool structured = true;
    #pragma unroll
    for (int i = 0; i < 8; ++i) {
        Areg[i] = -__expf(A_log[dB*DSTATE + n0 + i]);
        float expect = (float)(n0 + i + 1);
        structured = structured && (fabsf(Areg[i] + expect) < 1e-3f * expect);
        h[i] = 0.f;
    }

    // MLP stage 2 (mlph barrier-covered)
    if (tid < 32) {
        float acc = mlp_b2[tid];
        for (int k = 0; k < MLPH; ++k) acc += mlph[k]*mlp_W2[k*32 + tid];
        hfin[64 + tid] = acc;
    }

    // conv for chunk 0 into buffer 0
    conv_phase(0, &xc_s[0][0][0], xr, par, dA1, w1d, w0d, cw0, cw1, cw2, cw3, cb, xc_last);
    __syncthreads();

    // ---------------- main loop: 2 barriers per chunk ----------------
    for (int c = 0; c < NCHUNK; ++c) {
        const int buf = c & 1;
        const float* __restrict__ xcb = &xc_s[buf][0][0];

        // A2: [TC x 128] @ [128 x 20] -> dtraw(4) + Bs(16).
        // 240 threads, each does 2 tt rows (tt and tt+24), 2 j-cols.
        if (tid < 240) {
            const int tt0 = tid / 10;
            const int j0  = (tid - tt0*10) * 2;
            const float* p0 = &xprojT[j0][0];
            const float* p1 = &xprojT[j0+1][0];
            #pragma unroll
            for (int pass = 0; pass < 2; ++pass) {
                const int tt = tt0 + 24*pass;
                float a0 = 0.f, a1 = 0.f;
                const float* xrow = xcb + tt*XCP;
                #pragma unroll 4
                for (int d = 0; d < DINNER; d += 4) {
                    float4 xv = *(const float4*)(xrow + d);
                    float4 q0 = *(const float4*)(p0 + d);
                    float4 q1 = *(const float4*)(p1 + d);
                    a0 += xv.x*q0.x + xv.y*q0.y + xv.z*q0.z + xv.w*q0.w;
                    a1 += xv.x*q1.x + xv.y*q1.y + xv.z*q1.z + xv.w*q1.w;
                }
                if (j0 < 4) { float2 r = {a0, a1}; *(float2*)&dtraw[tt][j0] = r; }
                else        { float2 r = {a0, a1}; *(float2*)&Bs[tt][j0-4]  = r; }
            }
        }
        __syncthreads();

        // B: sequential scan. delta inline; dA via integer powers of r=exp(-delta)
        // when A_log has the arange structure (checked at runtime), else 8 exps.
        const float* __restrict__ xcd = xcb + dB;
        if (structured) {
            #pragma unroll 4
            for (int tt = 0; tt < TC; ++tt) {
                float4 dr = *(const float4*)&dtraw[tt][0];   // broadcast
                float dv = fmaf(dr.x, dtw0, fmaf(dr.y, dtw1,
                           fmaf(dr.z, dtw2, fmaf(dr.w, dtw3, dtb_r))));
                float e  = __expf(dv);
                float p  = 1.f + e;
                float r  = fast_rcp(p);                 // exp(-delta), exact-ish
                float dl = (dv > 80.f) ? dv : __logf(p); // delta = log1p(e^dv)
                float ux = dl * xcd[tt*XCP];
                float4 b0 = *(const float4*)&Bs[tt][n0];
                float4 b1 = *(const float4*)&Bs[tt][n0 + 4];
                // powers r^1..r^8, then scale by r^8 for the n0=8 half
                float r2 = r*r,  r3 = r2*r, r4 = r2*r2;
                float t4 = r4*r, t5 = r4*r2, t6 = r4*r3, t7 = r4*r4;
                float q  = (n0 == 0) ? 1.f : t7;
                h[0] = fmaf(r *q, h[0], ux*b0.x);
                h[1] = fmaf(r2*q, h[1], ux*b0.y);
                h[2] = fmaf(r3*q, h[2], ux*b0.z);
                h[3] = fmaf(r4*q, h[3], ux*b0.w);
                h[4] = fmaf(t4*q, h[4], ux*b1.x);
                h[5] = fmaf(t5*q, h[5], ux*b1.y);
                h[6] = fmaf(t6*q, h[6], ux*b1.z);
                h[7] = fmaf(t7*q, h[7], ux*b1.w);
            }
        } else {
            #pragma unroll 2
            for (int tt = 0; tt < TC; ++tt) {
                float4 dr = *(const float4*)&dtraw[tt][0];
                float dv = fmaf(dr.x, dtw0, fmaf(dr.y, dtw1,
                           fmaf(dr.z, dtw2, fmaf(dr.w, dtw3, dtb_r))));
                float dl = softplus_f(dv);
                float ux = dl * xcd[tt*XCP];
                float4 b0 = *(const float4*)&Bs[tt][n0];
                float4 b1 = *(const float4*)&Bs[tt][n0 + 4];
                h[0] = fmaf(__expf(dl*Areg[0]), h[0], ux*b0.x);
                h[1] = fmaf(__expf(dl*Areg[1]), h[1], ux*b0.y);
                h[2] = fmaf(__expf(dl*Areg[2]), h[2], ux*b0.z);
                h[3] = fmaf(__expf(dl*Areg[3]), h[3], ux*b0.w);
                h[4] = fmaf(__expf(dl*Areg[4]), h[4], ux*b1.x);
                h[5] = fmaf(__expf(dl*Areg[5]), h[5], ux*b1.y);
                h[6] = fmaf(__expf(dl*Areg[6]), h[6], ux*b1.z);
                h[7] = fmaf(__expf(dl*Areg[7]), h[7], ux*b1.w);
            }
        }

        // conv for next chunk into the other buffer (same basic block: the
        // scheduler interleaves this independent work into scan latency)
        if (c + 1 < NCHUNK) {
            conv_phase((c+1)*TC, &xc_s[1-buf][0][0], xr, par, dA1,
                       w1d, w0d, cw0, cw1, cw2, cw3, cb, xc_last);
        }
        __syncthreads();   // scan reads (dtraw/Bs/xcb) vs next A2 writes;
                           // conv writes vs next A2 reads
    }

    // ---------------- epilogue (t = 335 only) ----------------
    if (tid < DINNER) {   // z-gate
        float zv = fmaf(xr[LOOKBACK-1], w1s[DINNER+tid], w0s[DINNER+tid]);
        zsil[tid] = silu_f(zv);
    }
    if (tid < DSTATE) {   // C at t=335
        float acc = 0.f;
        for (int d = 0; d < DINNER; ++d) acc += xc_last[d]*xproj_W[d*36 + 20 + tid];
        Cl[tid] = acc;
    }
    __syncthreads();

    {   // y[d] = h·C + xc_last*D, gated by silu(z)
        float part = 0.f;
        #pragma unroll
        for (int i = 0; i < 8; ++i) part += h[i]*Cl[n0 + i];
        float other = __shfl_xor(part, 1);
        if ((tid & 1) == 0) {
            float y = part + other + xc_last[dB]*Dvec[dB];
            yv[dB] = y * zsil[dB];
        }
    }
    __syncthreads();

    if (tid < DMODEL) {   // out projection
        float acc = 0.f;
        for (int d = 0; d < DINNER; ++d) acc += yv[d]*out_W[d*DMODEL + tid];
        hfin[tid] = acc;
    }
    __syncthreads();

    if (tid < HORIZON) {  // head
        float acc = head_b[tid];
        for (int i = 0; i < 96; ++i) acc += hfin[i]*head_W[i*HORIZON + tid];
        out[b*HORIZON + tid] = acc;
    }
}

extern "C" void kernel_launch(void* const* d_in, const int* in_sizes, int n_in,
                              void* d_out, int out_size, void* d_ws, size_t ws_size,
                              hipStream_t stream) {
    (void)in_sizes; (void)n_in; (void)d_ws; (void)ws_size; (void)out_size;
    mamba_fused<<<BATCH, 256, 0, stream>>>(
        (const float*)d_in[0],  (const float*)d_in[1],  (const float*)d_in[2],
        (const float*)d_in[3],  (const float*)d_in[4],  (const float*)d_in[5],
        (const float*)d_in[6],  (const float*)d_in[7],  (const float*)d_in[8],
        (const float*)d_in[9],  (const float*)d_in[10], (const float*)d_in[11],
        (const float*)d_in[12], (const float*)d_in[13], (const float*)d_in[14],
        (const float*)d_in[15], (const float*)d_in[16], (const float*)d_in[17],
        (const float*)d_in[18], (float*)d_out);
}